// Round 3
// baseline (330.516 us; speedup 1.0000x reference)
//
#include <hip/hip_runtime.h>
#include <cstdint>
#include <cstddef>

typedef float f32x4 __attribute__((ext_vector_type(4)));
typedef long  lx2   __attribute__((ext_vector_type(2)));

#define AXB 2048   // amax/quant blocks for x  (each covers 4096 float4)
#define AWB 64     // amax/quant blocks for w  (each covers 4096 float4)

// ---------------------------------------------------------------------------
// helpers
// ---------------------------------------------------------------------------
__device__ __forceinline__ void async_copy16(const uint8_t* g, uint8_t* s) {
    __builtin_amdgcn_global_load_lds(
        (const __attribute__((address_space(1))) void*)g,
        (__attribute__((address_space(3))) void*)s,
        16 /*bytes*/, 0 /*offset*/, 0 /*aux*/);
}

// block-wide max; every thread returns the result. Caller must not reuse
// scr until after a subsequent __syncthreads().
__device__ __forceinline__ float block_max(float m, float* scr) {
#pragma unroll
    for (int o = 32; o > 0; o >>= 1) m = fmaxf(m, __shfl_down(m, o, 64));
    const int lane = threadIdx.x & 63, wid = threadIdx.x >> 6;
    if (lane == 0) scr[wid] = m;
    __syncthreads();
    const int nw = blockDim.x >> 6;
    m = scr[0];
    for (int j = 1; j < nw; ++j) m = fmaxf(m, scr[j]);
    return m;
}

// ---------------------------------------------------------------------------
// 1. per-block amax partials. Block-contiguous chunk of 4096 float4,
//    lane-contiguous loads, 16 independent unrolled loads per thread
//    (16 outstanding 16B loads/lane -> latency-hiding without occupancy).
//    blocks [0,AXB) -> x, blocks [AXB,AXB+AWB) -> w.
// ---------------------------------------------------------------------------
__global__ void amax_partials(const float4* __restrict__ x,
                              const float4* __restrict__ w,
                              float* __restrict__ part) {
    __shared__ float scr[8];
    const int b = blockIdx.x;
    const float4* p;
    int bi;
    if (b < AXB) { p = x; bi = b; }
    else         { p = w; bi = b - AXB; }
    const float4* base = p + (size_t)bi * 4096 + threadIdx.x;

    float m[16];
#pragma unroll
    for (int u = 0; u < 16; ++u) {
        float4 v = base[u * 256];
        m[u] = fmaxf(fmaxf(fabsf(v.x), fabsf(v.y)),
                     fmaxf(fabsf(v.z), fabsf(v.w)));
    }
#pragma unroll
    for (int s = 8; s > 0; s >>= 1)
#pragma unroll
        for (int u = 0; u < s; ++u) m[u] = fmaxf(m[u], m[u + s]);

    float r = block_max(m[0], scr);
    if (threadIdx.x == 0) part[b] = r;
}

// ---------------------------------------------------------------------------
// 2. quantize fp32 -> fp8 e4m3fn. Same block-contiguous / lane-contiguous
//    pattern: 16 float4 loads -> 16 packed dword stores per thread.
// ---------------------------------------------------------------------------
__global__ void quant_fused(const float4* __restrict__ x,
                            const float4* __restrict__ w,
                            const float* __restrict__ part,
                            unsigned* __restrict__ xq,
                            unsigned* __restrict__ wq) {
    __shared__ float scr[8];
    const int b = blockIdx.x;
    const float4* in;
    const float* pp;
    unsigned* out;
    int bi, np;
    if (b < AXB) { in = x; bi = b;       pp = part;       np = AXB; out = xq; }
    else         { in = w; bi = b - AXB; pp = part + AXB; np = AWB; out = wq; }

    float m = 0.0f;
    for (int i = threadIdx.x; i < np; i += blockDim.x) m = fmaxf(m, pp[i]);
    m = block_max(m, scr);
    const float r = 1.0f / fmaxf(m / 448.0f, 1e-12f);

    const float4* base = in + (size_t)bi * 4096 + threadIdx.x;
    unsigned* obase = out + (size_t)bi * 4096 + threadIdx.x;
#pragma unroll
    for (int u = 0; u < 16; ++u) {
        float4 v = base[u * 256];
        int p = 0;
        p = __builtin_amdgcn_cvt_pk_fp8_f32(v.x * r, v.y * r, p, false);
        p = __builtin_amdgcn_cvt_pk_fp8_f32(v.z * r, v.w * r, p, true);
        obase[u * 256] = (unsigned)p;
    }
}

// ---------------------------------------------------------------------------
// 3. fp8 GEMM: C[m,n] = (sum_k A[m,k]*B[n,k]) * scale + bias[n]
//    128x128 tile, BK=64, 256 thr (4 waves 2x2, each 64x64 via 4x4 MFMA tiles)
//    Fragment K-permutation: frag(quad,ks) = row bytes [quad*16 + ks*8, +8);
//    one ds_read_b128 per tile-row fetches both ks fragments conflict-free.
//    1D grid + XCD swizzle: the 8 N-tiles sharing an A-tile (131 KB) land on
//    one XCD consecutively -> A fetched ~once per XCD L2.
// ---------------------------------------------------------------------------
__global__ __launch_bounds__(256) void gemm_fp8_kernel(
    const uint8_t* __restrict__ A,   // [M][K] fp8
    const uint8_t* __restrict__ B,   // [N][K] fp8
    const float* __restrict__ bias,  // [N]
    const float* __restrict__ part,  // amax partials
    float* __restrict__ out,         // [M][N] fp32
    int M, int N, int K) {
    __shared__ long lds64[2048];     // 16 KiB: A tile [128][64B] + B tile
    uint8_t* Abase = (uint8_t*)lds64;
    uint8_t* Bbase = Abase + 8192;

    const int tid  = threadIdx.x;
    const int l    = tid & 63;
    const int w    = tid >> 6;
    const int lm   = l & 15;
    const int quad = l >> 4;
    const int wm   = (w >> 1) * 64;  // wave's M offset in tile
    const int wn   = (w & 1) * 64;   // wave's N offset in tile

    // XCD-aware swizzle: dispatch round-robins XCDs, so xcd = b & 7.
    // Give each XCD a contiguous band of 32 M-tiles; its 8 N-tiles per
    // M-tile are consecutive in local order (share A-tile in L2).
    const int b     = blockIdx.x;
    const int xcd   = b & 7;
    const int local = b >> 3;              // 0..255
    const size_t am0 = ((size_t)xcd * 32 + (local >> 3)) * 128;
    const size_t bn0 = (size_t)(local & 7) * 128;

    // per-tensor scales from partials (cheap block-local reduction)
    float* scr = (float*)lds64;
    float mx = 0.0f, mw = 0.0f;
    for (int i = tid; i < AXB; i += 256) mx = fmaxf(mx, part[i]);
    for (int i = tid; i < AWB; i += 256) mw = fmaxf(mw, part[AXB + i]);
    mx = block_max(mx, scr);
    mw = block_max(mw, scr + 8);
    const float scale = fmaxf(mx / 448.0f, 1e-12f) * fmaxf(mw / 448.0f, 1e-12f);
    __syncthreads();  // scr reads done before staging overwrites LDS

    f32x4 acc[4][4];
#pragma unroll
    for (int i = 0; i < 4; ++i)
#pragma unroll
        for (int j = 0; j < 4; ++j) acc[i][j] = (f32x4)0.0f;

    const int slot0 = w * 64 + l;  // 0..255; slot s -> row s/4, 16B-chunk s%4

    for (int kt = 0; kt < K; kt += 64) {
#pragma unroll
        for (int i = 0; i < 2; ++i) {
            const int s    = i * 256 + slot0;
            const int row  = s >> 2;
            const int chnk = s & 3;
            async_copy16(A + (am0 + row) * K + kt + chnk * 16,
                         Abase + (i * 4 + w) * 1024);
            async_copy16(B + (bn0 + row) * K + kt + chnk * 16,
                         Bbase + (i * 4 + w) * 1024);
        }
        __syncthreads();

        lx2 a[4], bb[4];
#pragma unroll
        for (int t = 0; t < 4; ++t) {
            a[t]  = *(const lx2*)&lds64[(wm + t * 16 + lm) * 8 + quad * 2];
            bb[t] = *(const lx2*)&lds64[1024 + (wn + t * 16 + lm) * 8 + quad * 2];
        }
#pragma unroll
        for (int ks = 0; ks < 2; ++ks)
#pragma unroll
            for (int mt = 0; mt < 4; ++mt)
#pragma unroll
                for (int nt = 0; nt < 4; ++nt)
                    acc[mt][nt] = __builtin_amdgcn_mfma_f32_16x16x32_fp8_fp8(
                        a[mt][ks], bb[nt][ks], acc[mt][nt], 0, 0, 0);
        __syncthreads();
    }

    // epilogue: D row = quad*4+reg, col = lm (within each 16x16 tile)
#pragma unroll
    for (int nt = 0; nt < 4; ++nt) {
        const int n = (int)bn0 + wn + nt * 16 + lm;
        const float bv = bias[n];
#pragma unroll
        for (int mt = 0; mt < 4; ++mt) {
            const size_t mrow = am0 + wm + mt * 16 + quad * 4;
#pragma unroll
            for (int r = 0; r < 4; ++r) {
                out[(mrow + r) * (size_t)N + n] = acc[mt][nt][r] * scale + bv;
            }
        }
    }
}

// ---------------------------------------------------------------------------
// host launcher
// ---------------------------------------------------------------------------
extern "C" void kernel_launch(void* const* d_in, const int* in_sizes, int n_in,
                              void* d_out, int out_size, void* d_ws,
                              size_t ws_size, hipStream_t stream) {
    const float* x      = (const float*)d_in[0];
    const float* weight = (const float*)d_in[1];
    const float* bias   = (const float*)d_in[2];
    float* out          = (float*)d_out;

    const int nx = in_sizes[0];        // M*K = 33554432
    const int nw = in_sizes[1];        // N*K = 1048576
    const int N  = in_sizes[2];        // 1024
    const int K  = nw / N;             // 1024
    const int M  = nx / K;             // 32768

    float* part     = (float*)d_ws;                 // AXB+AWB floats
    uint8_t* x_fp8  = (uint8_t*)d_ws + 16384;
    uint8_t* w_fp8  = x_fp8 + (size_t)nx;

    amax_partials<<<AXB + AWB, 256, 0, stream>>>(
        (const float4*)x, (const float4*)weight, part);
    quant_fused<<<AXB + AWB, 256, 0, stream>>>(
        (const float4*)x, (const float4*)weight, part,
        (unsigned*)x_fp8, (unsigned*)w_fp8);
    gemm_fp8_kernel<<<(M / 128) * (N / 128), 256, 0, stream>>>(
        x_fp8, w_fp8, bias, part, out, M, N, K);
}